// Round 6
// baseline (2543.603 us; speedup 1.0000x reference)
//
#include <hip/hip_runtime.h>
#include <hip/hip_bf16.h>
#include <stdint.h>

#define B_ 32
#define T_ 128
#define V_ 32000
#define E_ 256
#define HID_ 512

typedef float f32x4 __attribute__((ext_vector_type(4)));
typedef __bf16 bf16x8 __attribute__((ext_vector_type(8)));

// RNE float -> bf16 bits
static __device__ __forceinline__ unsigned short f2bf(float f) {
    unsigned int u = __float_as_uint(f);
    unsigned int r = (u + 0x7fffu + ((u >> 16) & 1u)) >> 16;
    return (unsigned short)r;
}

// ---------------------------------------------------------------------------
// K1: C[(t*B+b), :] = emb[x[b,t]] @ I + b1   (all f32)
// ---------------------------------------------------------------------------
__global__ __launch_bounds__(512) void k_embed_proj(
    const int* __restrict__ x, const float* __restrict__ emb,
    const float* __restrict__ I, const float* __restrict__ b1,
    float* __restrict__ C) {
    __shared__ float e[16][E_];
    const int tid = threadIdx.x;
    const int row0 = blockIdx.x * 16;

#pragma unroll
    for (int p = 0; p < 2; ++p) {
        int flat = p * 2048 + tid * 4;
        int i = flat >> 8;
        int c = flat & 255;
        int r = row0 + i;           // global row = t*B + b
        int t = r >> 5, b = r & 31;
        int xi = x[b * T_ + t];
        *(f32x4*)&e[i][c] = *(const f32x4*)(emb + (size_t)xi * E_ + c);
    }
    __syncthreads();

    float acc[16];
#pragma unroll
    for (int i = 0; i < 16; ++i) acc[i] = 0.f;
    const int j = tid;

    for (int k4 = 0; k4 < E_ / 4; ++k4) {
        float Iv[4];
#pragma unroll
        for (int q = 0; q < 4; ++q) Iv[q] = I[(size_t)(k4 * 4 + q) * HID_ + j];
#pragma unroll
        for (int i = 0; i < 16; ++i) {
            f32x4 ev = *(const f32x4*)&e[i][k4 * 4];
            acc[i] += ev[0] * Iv[0];
            acc[i] += ev[1] * Iv[1];
            acc[i] += ev[2] * Iv[2];
            acc[i] += ev[3] * Iv[3];
        }
    }
    float bv = b1[j];
#pragma unroll
    for (int i = 0; i < 16; ++i)
        C[(size_t)(row0 + i) * HID_ + j] = acc[i] + bv;
}

// ---------------------------------------------------------------------------
// K2a: pack H (f32 [512][512]) -> Hp (uint [256][512]):
// Hp[i][j] = bf16(H[2i][j]) | bf16(H[2i+1][j]) << 16
// ---------------------------------------------------------------------------
__global__ __launch_bounds__(256) void k_hpack(const float* __restrict__ H,
                                               unsigned int* __restrict__ Hp) {
    int idx = blockIdx.x * 256 + threadIdx.x;  // uint4 index
    int i = idx >> 7;            // packed row 0..255
    int j4 = (idx & 127) * 4;    // col
    f32x4 lo = *(const f32x4*)(H + (size_t)(2 * i) * HID_ + j4);
    f32x4 hi = *(const f32x4*)(H + (size_t)(2 * i + 1) * HID_ + j4);
    uint4 o;
    o.x = (unsigned)f2bf(lo[0]) | ((unsigned)f2bf(hi[0]) << 16);
    o.y = (unsigned)f2bf(lo[1]) | ((unsigned)f2bf(hi[1]) << 16);
    o.z = (unsigned)f2bf(lo[2]) | ((unsigned)f2bf(hi[2]) << 16);
    o.w = (unsigned)f2bf(lo[3]) | ((unsigned)f2bf(hi[3]) << 16);
    *(uint4*)(Hp + (size_t)i * HID_ + j4) = o;
}

// ---------------------------------------------------------------------------
// K2b: transpose + convert U (f32 [512][32000]) -> Ut (bf16 [32000][512])
// ---------------------------------------------------------------------------
__global__ __launch_bounds__(256) void k_transpose(const float* __restrict__ U,
                                                   unsigned short* __restrict__ Ut) {
    __shared__ float tile[64][65];
    const int tid = threadIdx.x;
    const int n0 = blockIdx.x * 64;
    const int k0 = blockIdx.y * 64;
    const int c = tid & 63;
    const int r = tid >> 6;
#pragma unroll
    for (int it = 0; it < 16; ++it) {
        int kk = it * 4 + r;
        tile[kk][c] = U[(size_t)(k0 + kk) * V_ + n0 + c];
    }
    __syncthreads();
#pragma unroll
    for (int it = 0; it < 16; ++it) {
        int nn = it * 4 + r;
        Ut[(size_t)(n0 + nn) * HID_ + k0 + c] = f2bf(tile[c][nn]);
    }
}

// ---------------------------------------------------------------------------
// K3: recurrence. 32 WGs (one per batch row) x 512 threads, NO cross-WG sync.
// H is CU-RESIDENT: thread j owns column j; rows 0..383 in 192 VGPRs
// (packed bf16 pairs), rows 384..511 in LDS Hl[64][512] (131 KB).
// amdgpu_waves_per_eu(2,2): pin 2 waves/EU so the allocator may use up to
// 256 VGPRs — WITHOUT this the heuristic targets 128 and spills Hreg to
// scratch (R4: VGPR_Count=128, 1802 us, L2-bound on spill re-reads).
// h double-buffered in LDS -> one barrier per step.
// ---------------------------------------------------------------------------
__global__ __attribute__((amdgpu_flat_work_group_size(512, 512),
                          amdgpu_waves_per_eu(2, 2)))
void k_recur(
    const float* __restrict__ C, const unsigned int* __restrict__ Hp,
    const float* __restrict__ init, unsigned short* __restrict__ hsb,
    float* __restrict__ lastState) {
    __shared__ float h[2][HID_];
    __shared__ unsigned int Hl[64][HID_];   // rows 384..511 packed
    const int tid = threadIdx.x;            // col j
    const int b = blockIdx.x;

    // ---- prologue: H column -> registers + LDS (one time) ----
    unsigned int Hreg[192];
#pragma unroll
    for (int i = 0; i < 192; ++i)
        Hreg[i] = Hp[(size_t)i * HID_ + tid];
#pragma unroll
    for (int p = 0; p < 64; ++p)
        Hl[p][tid] = Hp[(size_t)(192 + p) * HID_ + tid];

    h[0][tid] = init[b * HID_ + tid];
    __syncthreads();

    for (int t = 0; t < T_; ++t) {
        const int cur = t & 1;
        const float* hc = h[cur];
        float cv = C[((size_t)t * B_ + b) * HID_ + tid];  // issue early
        float a0 = 0.f, a1 = 0.f, a2 = 0.f, a3 = 0.f;
        // ---- register part: rows 0..383 (uints 0..191) ----
#pragma unroll
        for (int q = 0; q < 48; ++q) {
            f32x4 h0 = *(const f32x4*)&hc[q * 8];        // broadcast
            f32x4 h1 = *(const f32x4*)&hc[q * 8 + 4];
            unsigned int u0 = Hreg[q * 4 + 0];
            unsigned int u1 = Hreg[q * 4 + 1];
            unsigned int u2 = Hreg[q * 4 + 2];
            unsigned int u3 = Hreg[q * 4 + 3];
            a0 += __uint_as_float(u0 << 16) * h0[0];
            a1 += __uint_as_float(u0 & 0xffff0000u) * h0[1];
            a2 += __uint_as_float(u1 << 16) * h0[2];
            a3 += __uint_as_float(u1 & 0xffff0000u) * h0[3];
            a0 += __uint_as_float(u2 << 16) * h1[0];
            a1 += __uint_as_float(u2 & 0xffff0000u) * h1[1];
            a2 += __uint_as_float(u3 << 16) * h1[2];
            a3 += __uint_as_float(u3 & 0xffff0000u) * h1[3];
        }
        // ---- LDS part: rows 384..511 (Hl[0..63]) ----
#pragma unroll
        for (int p = 0; p < 64; p += 2) {
            unsigned int u0 = Hl[p][tid];       // 2 lanes/bank: free
            unsigned int u1 = Hl[p + 1][tid];
            f32x4 hp = *(const f32x4*)&hc[384 + 2 * p]; // 16B-aligned (p even)
            a0 += __uint_as_float(u0 << 16) * hp[0];
            a1 += __uint_as_float(u0 & 0xffff0000u) * hp[1];
            a2 += __uint_as_float(u1 << 16) * hp[2];
            a3 += __uint_as_float(u1 & 0xffff0000u) * hp[3];
        }
        float v = fmaxf(cv + ((a0 + a1) + (a2 + a3)), 0.f);
        h[cur ^ 1][tid] = v;       // write NEXT buffer: no read hazard
        hsb[((size_t)t * B_ + b) * HID_ + tid] = f2bf(v);
        __syncthreads();           // next-buffer writes visible for next step
    }
    lastState[b * HID_ + tid] = h[T_ & 1][tid];
}

// ---------------------------------------------------------------------------
// K4: logits = hs[4096x512](bf16) @ Ut^T (bf16 [N][K]) + b2  (unchanged)
// ---------------------------------------------------------------------------
#define LDK 72
__global__ __launch_bounds__(256) void k_gemm(
    const unsigned short* __restrict__ A, const unsigned short* __restrict__ Bt,
    const float* __restrict__ b2, float* __restrict__ out) {
    __shared__ unsigned short As[128 * LDK];
    __shared__ unsigned short Bs[128 * LDK];
    const int tid = threadIdx.x;
    const int l = tid & 63;
    const int w = tid >> 6;
    const int wm = w >> 1, wn = w & 1;
    const int n0 = blockIdx.x * 128;
    const int m0 = blockIdx.y * 128;

    f32x4 acc[4][4] = {};

    for (int kt = 0; kt < 8; ++kt) {
        const int kk = kt * 64;
        uint4 ra[4], rb[4];
#pragma unroll
        for (int i = 0; i < 4; ++i) {
            int flat = i * 256 + tid;
            int row = flat >> 3;
            int c8 = (flat & 7) * 8;
            ra[i] = *(const uint4*)(A + (size_t)(m0 + row) * HID_ + kk + c8);
            rb[i] = *(const uint4*)(Bt + (size_t)(n0 + row) * HID_ + kk + c8);
        }
        __syncthreads();
#pragma unroll
        for (int i = 0; i < 4; ++i) {
            int flat = i * 256 + tid;
            int row = flat >> 3;
            int c8 = (flat & 7) * 8;
            *(uint4*)(As + row * LDK + c8) = ra[i];
            *(uint4*)(Bs + row * LDK + c8) = rb[i];
        }
        __syncthreads();
#pragma unroll
        for (int ks = 0; ks < 2; ++ks) {
            bf16x8 af[4], bfr[4];
#pragma unroll
            for (int f = 0; f < 4; ++f) {
                af[f]  = *(const bf16x8*)(As + (wm * 64 + f * 16 + (l & 15)) * LDK + ks * 32 + (l >> 4) * 8);
                bfr[f] = *(const bf16x8*)(Bs + (wn * 64 + f * 16 + (l & 15)) * LDK + ks * 32 + (l >> 4) * 8);
            }
#pragma unroll
            for (int fm = 0; fm < 4; ++fm)
#pragma unroll
                for (int fn = 0; fn < 4; ++fn)
                    acc[fm][fn] = __builtin_amdgcn_mfma_f32_16x16x32_bf16(
                        af[fm], bfr[fn], acc[fm][fn], 0, 0, 0);
        }
    }

    const int cl = l & 15;
    const int q4 = (l >> 4) * 4;
    float b2v[4];
#pragma unroll
    for (int fn = 0; fn < 4; ++fn) b2v[fn] = b2[n0 + wn * 64 + fn * 16 + cl];
#pragma unroll
    for (int fm = 0; fm < 4; ++fm) {
#pragma unroll
        for (int r = 0; r < 4; ++r) {
            int rg = m0 + wm * 64 + fm * 16 + q4 + r; // A-row = t*B + b
            int t = rg >> 5, b = rg & 31;
            float* orow = out + (size_t)(b * T_ + t) * V_ + n0 + wn * 64 + cl;
#pragma unroll
            for (int fn = 0; fn < 4; ++fn)
                orow[fn * 16] = acc[fm][fn][r] + b2v[fn];
        }
    }
}

// ---------------------------------------------------------------------------
extern "C" void kernel_launch(void* const* d_in, const int* in_sizes, int n_in,
                              void* d_out, int out_size, void* d_ws, size_t ws_size,
                              hipStream_t stream) {
    const int* x      = (const int*)d_in[0];
    const float* init = (const float*)d_in[1];
    const float* emb  = (const float*)d_in[2];
    const float* H    = (const float*)d_in[3];
    const float* I    = (const float*)d_in[4];
    const float* b1   = (const float*)d_in[5];
    const float* U    = (const float*)d_in[6];
    const float* b2   = (const float*)d_in[7];
    float* out = (float*)d_out;

    // workspace layout:
    //   [0,8MB)     C      f32  [T*B][512]
    //   [8,12MB)    hsb    bf16 [T*B][512]
    //   [12,~45MB)  Ut     bf16 [32000][512]
    //   [46MB,..)   Hp     uint [256][512]  packed bf16 pairs (512 KB)
    char* ws = (char*)d_ws;
    float* C            = (float*)ws;
    unsigned short* hsb = (unsigned short*)(ws + ((size_t)8 << 20));
    unsigned short* Ut  = (unsigned short*)(ws + ((size_t)12 << 20));
    unsigned int* Hp    = (unsigned int*)(ws + ((size_t)46 << 20));
    float* lastState = out + (size_t)B_ * T_ * V_;

    k_embed_proj<<<256, 512, 0, stream>>>(x, emb, I, b1, C);
    k_hpack<<<128, 256, 0, stream>>>(H, Hp);
    k_transpose<<<dim3(500, 8), 256, 0, stream>>>(U, Ut);
    k_recur<<<B_, 512, 0, stream>>>(C, Hp, init, hsb, lastState);
    k_gemm<<<dim3(250, 32), 256, 0, stream>>>(hsb, Ut, b2, out);
}

// Round 7
// 2344.674 us; speedup vs baseline: 1.0848x; 1.0848x over previous
//
#include <hip/hip_runtime.h>
#include <hip/hip_bf16.h>
#include <stdint.h>

#define B_ 32
#define T_ 128
#define V_ 32000
#define E_ 256
#define HID_ 512

typedef float f32x4 __attribute__((ext_vector_type(4)));
typedef unsigned int u32x4 __attribute__((ext_vector_type(4)));
typedef __bf16 bf16x8 __attribute__((ext_vector_type(8)));

// RNE float -> bf16 bits
static __device__ __forceinline__ unsigned short f2bf(float f) {
    unsigned int u = __float_as_uint(f);
    unsigned int r = (u + 0x7fffu + ((u >> 16) & 1u)) >> 16;
    return (unsigned short)r;
}

// ---------------------------------------------------------------------------
// K1: C[(t*B+b), :] = emb[x[b,t]] @ I + b1   (all f32)
// ---------------------------------------------------------------------------
__global__ __launch_bounds__(512) void k_embed_proj(
    const int* __restrict__ x, const float* __restrict__ emb,
    const float* __restrict__ I, const float* __restrict__ b1,
    float* __restrict__ C) {
    __shared__ float e[16][E_];
    const int tid = threadIdx.x;
    const int row0 = blockIdx.x * 16;

#pragma unroll
    for (int p = 0; p < 2; ++p) {
        int flat = p * 2048 + tid * 4;
        int i = flat >> 8;
        int c = flat & 255;
        int r = row0 + i;           // global row = t*B + b
        int t = r >> 5, b = r & 31;
        int xi = x[b * T_ + t];
        *(f32x4*)&e[i][c] = *(const f32x4*)(emb + (size_t)xi * E_ + c);
    }
    __syncthreads();

    float acc[16];
#pragma unroll
    for (int i = 0; i < 16; ++i) acc[i] = 0.f;
    const int j = tid;

    for (int k4 = 0; k4 < E_ / 4; ++k4) {
        float Iv[4];
#pragma unroll
        for (int q = 0; q < 4; ++q) Iv[q] = I[(size_t)(k4 * 4 + q) * HID_ + j];
#pragma unroll
        for (int i = 0; i < 16; ++i) {
            f32x4 ev = *(const f32x4*)&e[i][k4 * 4];
            acc[i] += ev[0] * Iv[0];
            acc[i] += ev[1] * Iv[1];
            acc[i] += ev[2] * Iv[2];
            acc[i] += ev[3] * Iv[3];
        }
    }
    float bv = b1[j];
#pragma unroll
    for (int i = 0; i < 16; ++i)
        C[(size_t)(row0 + i) * HID_ + j] = acc[i] + bv;
}

// ---------------------------------------------------------------------------
// K2a: pack H (f32 [512][512]) -> Hpp (uint4 [32][1024]) in the EXACT
// per-thread order k_recur consumes:
//   thread tid = rg*128+cg (rg=tid>>7, cg=tid&127) owns rows rg*64..+63,
//   cols cg*4..+3.
//   i4<24 (VGPR part):  c2=i4>>1, p=i4&1, rows r0=rg*64+c2*4+2p, r0+1
//   i4>=24 (LDS part):  m=i4-24, c2=m>>1, p=m&1, rows r0=rg*64+48+c2*4+2p
//   component q: bf(H[r0][cg*4+q]) | bf(H[r0+1][cg*4+q])<<16
// ---------------------------------------------------------------------------
__global__ __launch_bounds__(256) void k_hpack(const float* __restrict__ H,
                                               u32x4* __restrict__ Hpp) {
    int idx = blockIdx.x * 256 + threadIdx.x;   // 0..32767
    int i4 = idx >> 10;
    int tid = idx & 1023;
    int rg = tid >> 7, cg = tid & 127;
    int r0;
    if (i4 < 24) {
        int c2 = i4 >> 1, p = i4 & 1;
        r0 = rg * 64 + c2 * 4 + 2 * p;
    } else {
        int m = i4 - 24;
        int c2 = m >> 1, p = m & 1;
        r0 = rg * 64 + 48 + c2 * 4 + 2 * p;
    }
    int col = cg * 4;
    f32x4 lo = *(const f32x4*)(H + (size_t)r0 * HID_ + col);
    f32x4 hi = *(const f32x4*)(H + (size_t)(r0 + 1) * HID_ + col);
    u32x4 o;
#pragma unroll
    for (int q = 0; q < 4; ++q)
        o[q] = (unsigned)f2bf(lo[q]) | ((unsigned)f2bf(hi[q]) << 16);
    Hpp[(size_t)i4 * 1024 + tid] = o;
}

// ---------------------------------------------------------------------------
// K2b: transpose + convert U (f32 [512][32000]) -> Ut (bf16 [32000][512])
// ---------------------------------------------------------------------------
__global__ __launch_bounds__(256) void k_transpose(const float* __restrict__ U,
                                                   unsigned short* __restrict__ Ut) {
    __shared__ float tile[64][65];
    const int tid = threadIdx.x;
    const int n0 = blockIdx.x * 64;
    const int k0 = blockIdx.y * 64;
    const int c = tid & 63;
    const int r = tid >> 6;
#pragma unroll
    for (int it = 0; it < 16; ++it) {
        int kk = it * 4 + r;
        tile[kk][c] = U[(size_t)(k0 + kk) * V_ + n0 + c];
    }
    __syncthreads();
#pragma unroll
    for (int it = 0; it < 16; ++it) {
        int nn = it * 4 + r;
        Ut[(size_t)(n0 + nn) * HID_ + k0 + c] = f2bf(tile[c][nn]);
    }
}

// ---------------------------------------------------------------------------
// K3: recurrence. 32 WGs (one per batch row) x 1024 threads, no cross-WG
// sync. Thread (rg=tid>>7, cg=tid&127) owns a 64-row x 4-col block of H:
// 24 u32x4 (96 VGPR, fits the compiler's 128 budget) + 8 u32x4 in LDS
// (128 KB). h double-buffered in LDS; per-step: 16 b128 h-broadcast reads
// (x4 column reuse), 8 b128 Hl reads, f32x4 partial write, 8-way reduce by
// tid<512. ~2.2us LDS + ~1.9us VALU per step, overlapped.
// ---------------------------------------------------------------------------
__global__ __launch_bounds__(1024) void k_recur(
    const float* __restrict__ C, const u32x4* __restrict__ Hpp,
    const float* __restrict__ init, unsigned short* __restrict__ hsb,
    float* __restrict__ lastState) {
    __shared__ u32x4 Hl[8][1024];      // rows 48..63 of each rg-slice: 128 KB
    __shared__ float hbuf[2][HID_];    // 4 KB
    __shared__ float ps[8][HID_];      // 16 KB
    const int tid = threadIdx.x;
    const int b = blockIdx.x;
    const int rg = tid >> 7;           // row-group 0..7
    const int cg = tid & 127;          // col-group 0..127
    const int hb = rg * 64;

    // ---- prologue: H block -> 24 u32x4 registers + 8 u32x4 LDS ----
    u32x4 hr[24];
#pragma unroll
    for (int i = 0; i < 24; ++i)
        hr[i] = Hpp[(size_t)i * 1024 + tid];
#pragma unroll
    for (int m = 0; m < 8; ++m)
        Hl[m][tid] = Hpp[(size_t)(24 + m) * 1024 + tid];

    if (tid < HID_) hbuf[0][tid] = init[b * HID_ + tid];
    __syncthreads();

    for (int t = 0; t < T_; ++t) {
        const int cur = t & 1;
        const float* hc = hbuf[cur];
        float cv = 0.f;
        if (tid < HID_) cv = C[((size_t)t * B_ + b) * HID_ + tid]; // early
        f32x4 a = {0.f, 0.f, 0.f, 0.f};
        // ---- VGPR part: rows hb+0 .. hb+47 ----
#pragma unroll
        for (int c2 = 0; c2 < 12; ++c2) {
            f32x4 hv = *(const f32x4*)&hc[hb + c2 * 4];  // wave-uniform bcast
            u32x4 ua = hr[2 * c2];
            u32x4 ub = hr[2 * c2 + 1];
#pragma unroll
            for (int q = 0; q < 4; ++q) {
                a[q] += __uint_as_float(ua[q] << 16) * hv[0];
                a[q] += __uint_as_float(ua[q] & 0xffff0000u) * hv[1];
                a[q] += __uint_as_float(ub[q] << 16) * hv[2];
                a[q] += __uint_as_float(ub[q] & 0xffff0000u) * hv[3];
            }
        }
        // ---- LDS part: rows hb+48 .. hb+63 ----
#pragma unroll
        for (int c2 = 0; c2 < 4; ++c2) {
            f32x4 hv = *(const f32x4*)&hc[hb + 48 + c2 * 4];
            u32x4 ua = Hl[2 * c2][tid];       // sequential: conflict-free
            u32x4 ub = Hl[2 * c2 + 1][tid];
#pragma unroll
            for (int q = 0; q < 4; ++q) {
                a[q] += __uint_as_float(ua[q] << 16) * hv[0];
                a[q] += __uint_as_float(ua[q] & 0xffff0000u) * hv[1];
                a[q] += __uint_as_float(ub[q] << 16) * hv[2];
                a[q] += __uint_as_float(ub[q] & 0xffff0000u) * hv[3];
            }
        }
        *(f32x4*)&ps[rg][cg * 4] = a;        // sequential: conflict-free
        __syncthreads();                     // ps visible

        if (tid < HID_) {
            float v = cv;
#pragma unroll
            for (int g = 0; g < 8; ++g) v += ps[g][tid];
            v = fmaxf(v, 0.f);
            hbuf[cur ^ 1][tid] = v;
            hsb[((size_t)t * B_ + b) * HID_ + tid] = f2bf(v);
        }
        __syncthreads();                     // h[nxt] visible
    }
    if (tid < HID_) lastState[b * HID_ + tid] = hbuf[0][tid]; // 128 even
}

// ---------------------------------------------------------------------------
// K4: logits = hs[4096x512](bf16) @ Ut^T (bf16 [N][K]) + b2  (unchanged)
// ---------------------------------------------------------------------------
#define LDK 72
__global__ __launch_bounds__(256) void k_gemm(
    const unsigned short* __restrict__ A, const unsigned short* __restrict__ Bt,
    const float* __restrict__ b2, float* __restrict__ out) {
    __shared__ unsigned short As[128 * LDK];
    __shared__ unsigned short Bs[128 * LDK];
    const int tid = threadIdx.x;
    const int l = tid & 63;
    const int w = tid >> 6;
    const int wm = w >> 1, wn = w & 1;
    const int n0 = blockIdx.x * 128;
    const int m0 = blockIdx.y * 128;

    f32x4 acc[4][4] = {};

    for (int kt = 0; kt < 8; ++kt) {
        const int kk = kt * 64;
        uint4 ra[4], rb[4];
#pragma unroll
        for (int i = 0; i < 4; ++i) {
            int flat = i * 256 + tid;
            int row = flat >> 3;
            int c8 = (flat & 7) * 8;
            ra[i] = *(const uint4*)(A + (size_t)(m0 + row) * HID_ + kk + c8);
            rb[i] = *(const uint4*)(Bt + (size_t)(n0 + row) * HID_ + kk + c8);
        }
        __syncthreads();
#pragma unroll
        for (int i = 0; i < 4; ++i) {
            int flat = i * 256 + tid;
            int row = flat >> 3;
            int c8 = (flat & 7) * 8;
            *(uint4*)(As + row * LDK + c8) = ra[i];
            *(uint4*)(Bs + row * LDK + c8) = rb[i];
        }
        __syncthreads();
#pragma unroll
        for (int ks = 0; ks < 2; ++ks) {
            bf16x8 af[4], bfr[4];
#pragma unroll
            for (int f = 0; f < 4; ++f) {
                af[f]  = *(const bf16x8*)(As + (wm * 64 + f * 16 + (l & 15)) * LDK + ks * 32 + (l >> 4) * 8);
                bfr[f] = *(const bf16x8*)(Bs + (wn * 64 + f * 16 + (l & 15)) * LDK + ks * 32 + (l >> 4) * 8);
            }
#pragma unroll
            for (int fm = 0; fm < 4; ++fm)
#pragma unroll
                for (int fn = 0; fn < 4; ++fn)
                    acc[fm][fn] = __builtin_amdgcn_mfma_f32_16x16x32_bf16(
                        af[fm], bfr[fn], acc[fm][fn], 0, 0, 0);
        }
    }

    const int cl = l & 15;
    const int q4 = (l >> 4) * 4;
    float b2v[4];
#pragma unroll
    for (int fn = 0; fn < 4; ++fn) b2v[fn] = b2[n0 + wn * 64 + fn * 16 + cl];
#pragma unroll
    for (int fm = 0; fm < 4; ++fm) {
#pragma unroll
        for (int r = 0; r < 4; ++r) {
            int rg = m0 + wm * 64 + fm * 16 + q4 + r; // A-row = t*B + b
            int t = rg >> 5, b = rg & 31;
            float* orow = out + (size_t)(b * T_ + t) * V_ + n0 + wn * 64 + cl;
#pragma unroll
            for (int fn = 0; fn < 4; ++fn)
                orow[fn * 16] = acc[fm][fn][r] + b2v[fn];
        }
    }
}

// ---------------------------------------------------------------------------
extern "C" void kernel_launch(void* const* d_in, const int* in_sizes, int n_in,
                              void* d_out, int out_size, void* d_ws, size_t ws_size,
                              hipStream_t stream) {
    const int* x      = (const int*)d_in[0];
    const float* init = (const float*)d_in[1];
    const float* emb  = (const float*)d_in[2];
    const float* H    = (const float*)d_in[3];
    const float* I    = (const float*)d_in[4];
    const float* b1   = (const float*)d_in[5];
    const float* U    = (const float*)d_in[6];
    const float* b2   = (const float*)d_in[7];
    float* out = (float*)d_out;

    // workspace layout:
    //   [0,8MB)     C      f32  [T*B][512]
    //   [8,12MB)    hsb    bf16 [T*B][512]
    //   [12,~45MB)  Ut     bf16 [32000][512]
    //   [46MB,..)   Hpp    u32x4 [32][1024] packed per-thread order (512 KB)
    char* ws = (char*)d_ws;
    float* C            = (float*)ws;
    unsigned short* hsb = (unsigned short*)(ws + ((size_t)8 << 20));
    unsigned short* Ut  = (unsigned short*)(ws + ((size_t)12 << 20));
    u32x4* Hpp          = (u32x4*)(ws + ((size_t)46 << 20));
    float* lastState = out + (size_t)B_ * T_ * V_;

    k_embed_proj<<<256, 512, 0, stream>>>(x, emb, I, b1, C);
    k_hpack<<<128, 256, 0, stream>>>(H, Hpp);
    k_transpose<<<dim3(500, 8), 256, 0, stream>>>(U, Ut);
    k_recur<<<B_, 1024, 0, stream>>>(C, Hpp, init, hsb, lastState);
    k_gemm<<<dim3(250, 32), 256, 0, stream>>>(hsb, Ut, b2, out);
}

// Round 8
// 2316.914 us; speedup vs baseline: 1.0978x; 1.0120x over previous
//
#include <hip/hip_runtime.h>
#include <hip/hip_bf16.h>
#include <stdint.h>

#define B_ 32
#define T_ 128
#define V_ 32000
#define E_ 256
#define HID_ 512

typedef float f32x4 __attribute__((ext_vector_type(4)));
typedef unsigned int u32x4 __attribute__((ext_vector_type(4)));
typedef __bf16 bf16x8 __attribute__((ext_vector_type(8)));

// RNE float -> bf16 bits
static __device__ __forceinline__ unsigned short f2bf(float f) {
    unsigned int u = __float_as_uint(f);
    unsigned int r = (u + 0x7fffu + ((u >> 16) & 1u)) >> 16;
    return (unsigned short)r;
}

// ---------------------------------------------------------------------------
// K1: C[(t*B+b), :] = emb[x[b,t]] @ I + b1   (all f32)
// ---------------------------------------------------------------------------
__global__ __launch_bounds__(512) void k_embed_proj(
    const int* __restrict__ x, const float* __restrict__ emb,
    const float* __restrict__ I, const float* __restrict__ b1,
    float* __restrict__ C) {
    __shared__ float e[16][E_];
    const int tid = threadIdx.x;
    const int row0 = blockIdx.x * 16;

#pragma unroll
    for (int p = 0; p < 2; ++p) {
        int flat = p * 2048 + tid * 4;
        int i = flat >> 8;
        int c = flat & 255;
        int r = row0 + i;           // global row = t*B + b
        int t = r >> 5, b = r & 31;
        int xi = x[b * T_ + t];
        *(f32x4*)&e[i][c] = *(const f32x4*)(emb + (size_t)xi * E_ + c);
    }
    __syncthreads();

    float acc[16];
#pragma unroll
    for (int i = 0; i < 16; ++i) acc[i] = 0.f;
    const int j = tid;

    for (int k4 = 0; k4 < E_ / 4; ++k4) {
        float Iv[4];
#pragma unroll
        for (int q = 0; q < 4; ++q) Iv[q] = I[(size_t)(k4 * 4 + q) * HID_ + j];
#pragma unroll
        for (int i = 0; i < 16; ++i) {
            f32x4 ev = *(const f32x4*)&e[i][k4 * 4];
            acc[i] += ev[0] * Iv[0];
            acc[i] += ev[1] * Iv[1];
            acc[i] += ev[2] * Iv[2];
            acc[i] += ev[3] * Iv[3];
        }
    }
    float bv = b1[j];
#pragma unroll
    for (int i = 0; i < 16; ++i)
        C[(size_t)(row0 + i) * HID_ + j] = acc[i] + bv;
}

// ---------------------------------------------------------------------------
// K2a: pack H (f32 [512][512]) -> Hpp (uint4 [32][1024]) in the EXACT
// per-thread order k_recur consumes (see R6 comment; unchanged).
// ---------------------------------------------------------------------------
__global__ __launch_bounds__(256) void k_hpack(const float* __restrict__ H,
                                               u32x4* __restrict__ Hpp) {
    int idx = blockIdx.x * 256 + threadIdx.x;   // 0..32767
    int i4 = idx >> 10;
    int tid = idx & 1023;
    int rg = tid >> 7, cg = tid & 127;
    int r0;
    if (i4 < 24) {
        int c2 = i4 >> 1, p = i4 & 1;
        r0 = rg * 64 + c2 * 4 + 2 * p;
    } else {
        int m = i4 - 24;
        int c2 = m >> 1, p = m & 1;
        r0 = rg * 64 + 48 + c2 * 4 + 2 * p;
    }
    int col = cg * 4;
    f32x4 lo = *(const f32x4*)(H + (size_t)r0 * HID_ + col);
    f32x4 hi = *(const f32x4*)(H + (size_t)(r0 + 1) * HID_ + col);
    u32x4 o;
#pragma unroll
    for (int q = 0; q < 4; ++q)
        o[q] = (unsigned)f2bf(lo[q]) | ((unsigned)f2bf(hi[q]) << 16);
    Hpp[(size_t)i4 * 1024 + tid] = o;
}

// ---------------------------------------------------------------------------
// K2b: transpose + convert U (f32 [512][32000]) -> Ut (bf16 [32000][512])
// ---------------------------------------------------------------------------
__global__ __launch_bounds__(256) void k_transpose(const float* __restrict__ U,
                                                   unsigned short* __restrict__ Ut) {
    __shared__ float tile[64][65];
    const int tid = threadIdx.x;
    const int n0 = blockIdx.x * 64;
    const int k0 = blockIdx.y * 64;
    const int c = tid & 63;
    const int r = tid >> 6;
#pragma unroll
    for (int it = 0; it < 16; ++it) {
        int kk = it * 4 + r;
        tile[kk][c] = U[(size_t)(k0 + kk) * V_ + n0 + c];
    }
    __syncthreads();
#pragma unroll
    for (int it = 0; it < 16; ++it) {
        int nn = it * 4 + r;
        Ut[(size_t)(n0 + nn) * HID_ + k0 + c] = f2bf(tile[c][nn]);
    }
}

// ---------------------------------------------------------------------------
// K3: recurrence. 32 WGs x 1024 threads. Thread (rg,cg) owns 64 rows x 4
// cols of H: 96 scalar uints in VGPRs + 8 u32x4 in LDS (128 KB).
// __launch_bounds__(1024,4): 16 waves = 4/EU -> VGPR cap 128.
// asm "+v" pin after the prologue makes the 96 H-words OPAQUE so the
// compiler cannot sink the loads into the t-loop (R6 failure: VGPR=64,
// loads re-issued per step -> L2-bound 1.6 ms).
// ---------------------------------------------------------------------------
#define PIN8(k) asm volatile("" : "+v"(hr[k+0]), "+v"(hr[k+1]), "+v"(hr[k+2]), \
    "+v"(hr[k+3]), "+v"(hr[k+4]), "+v"(hr[k+5]), "+v"(hr[k+6]), "+v"(hr[k+7]))

__global__ __launch_bounds__(1024, 4) void k_recur(
    const float* __restrict__ C, const u32x4* __restrict__ Hpp,
    const float* __restrict__ init, unsigned short* __restrict__ hsb,
    float* __restrict__ lastState) {
    __shared__ u32x4 Hl[8][1024];      // rows 48..63 of each rg-slice: 128 KB
    __shared__ float hbuf[2][HID_];    // 4 KB
    __shared__ float ps[8][HID_];      // 16 KB
    const int tid = threadIdx.x;
    const int b = blockIdx.x;
    const int rg = tid >> 7;           // row-group 0..7
    const int cg = tid & 127;          // col-group 0..127
    const int hb = rg * 64;

    // ---- prologue: H block -> 96 scalar uints + 8 u32x4 LDS ----
    unsigned int hr[96];
#pragma unroll
    for (int i = 0; i < 24; ++i) {
        u32x4 v = Hpp[(size_t)i * 1024 + tid];
        hr[4 * i + 0] = v[0]; hr[4 * i + 1] = v[1];
        hr[4 * i + 2] = v[2]; hr[4 * i + 3] = v[3];
    }
    PIN8(0);  PIN8(8);  PIN8(16); PIN8(24); PIN8(32); PIN8(40);
    PIN8(48); PIN8(56); PIN8(64); PIN8(72); PIN8(80); PIN8(88);
#pragma unroll
    for (int m = 0; m < 8; ++m)
        Hl[m][tid] = Hpp[(size_t)(24 + m) * 1024 + tid];

    if (tid < HID_) hbuf[0][tid] = init[b * HID_ + tid];
    __syncthreads();

    for (int t = 0; t < T_; ++t) {
        const int cur = t & 1;
        const float* hc = hbuf[cur];
        float cv = 0.f;
        if (tid < HID_) cv = C[((size_t)t * B_ + b) * HID_ + tid]; // early
        f32x4 a = {0.f, 0.f, 0.f, 0.f};
        // ---- VGPR part: rows hb+0 .. hb+47 ----
#pragma unroll
        for (int c2 = 0; c2 < 12; ++c2) {
            f32x4 hv = *(const f32x4*)&hc[hb + c2 * 4];  // wave-uniform bcast
#pragma unroll
            for (int q = 0; q < 4; ++q) {
                unsigned int ua = hr[8 * c2 + q];
                unsigned int ub = hr[8 * c2 + 4 + q];
                a[q] += __uint_as_float(ua << 16) * hv[0];
                a[q] += __uint_as_float(ua & 0xffff0000u) * hv[1];
                a[q] += __uint_as_float(ub << 16) * hv[2];
                a[q] += __uint_as_float(ub & 0xffff0000u) * hv[3];
            }
        }
        // ---- LDS part: rows hb+48 .. hb+63 ----
#pragma unroll
        for (int c2 = 0; c2 < 4; ++c2) {
            f32x4 hv = *(const f32x4*)&hc[hb + 48 + c2 * 4];
            u32x4 ua = Hl[2 * c2][tid];       // sequential: conflict-free
            u32x4 ub = Hl[2 * c2 + 1][tid];
#pragma unroll
            for (int q = 0; q < 4; ++q) {
                a[q] += __uint_as_float(ua[q] << 16) * hv[0];
                a[q] += __uint_as_float(ua[q] & 0xffff0000u) * hv[1];
                a[q] += __uint_as_float(ub[q] << 16) * hv[2];
                a[q] += __uint_as_float(ub[q] & 0xffff0000u) * hv[3];
            }
        }
        *(f32x4*)&ps[rg][cg * 4] = a;        // sequential: conflict-free
        __syncthreads();                     // ps visible

        if (tid < HID_) {
            float v = cv;
#pragma unroll
            for (int g = 0; g < 8; ++g) v += ps[g][tid];
            v = fmaxf(v, 0.f);
            hbuf[cur ^ 1][tid] = v;
            hsb[((size_t)t * B_ + b) * HID_ + tid] = f2bf(v);
        }
        __syncthreads();                     // h[nxt] visible
    }
    if (tid < HID_) lastState[b * HID_ + tid] = hbuf[0][tid]; // 128 even
}

// ---------------------------------------------------------------------------
// K4: logits = hs[4096x512](bf16) @ Ut^T (bf16 [N][K]) + b2  (unchanged)
// ---------------------------------------------------------------------------
#define LDK 72
__global__ __launch_bounds__(256) void k_gemm(
    const unsigned short* __restrict__ A, const unsigned short* __restrict__ Bt,
    const float* __restrict__ b2, float* __restrict__ out) {
    __shared__ unsigned short As[128 * LDK];
    __shared__ unsigned short Bs[128 * LDK];
    const int tid = threadIdx.x;
    const int l = tid & 63;
    const int w = tid >> 6;
    const int wm = w >> 1, wn = w & 1;
    const int n0 = blockIdx.x * 128;
    const int m0 = blockIdx.y * 128;

    f32x4 acc[4][4] = {};

    for (int kt = 0; kt < 8; ++kt) {
        const int kk = kt * 64;
        uint4 ra[4], rb[4];
#pragma unroll
        for (int i = 0; i < 4; ++i) {
            int flat = i * 256 + tid;
            int row = flat >> 3;
            int c8 = (flat & 7) * 8;
            ra[i] = *(const uint4*)(A + (size_t)(m0 + row) * HID_ + kk + c8);
            rb[i] = *(const uint4*)(Bt + (size_t)(n0 + row) * HID_ + kk + c8);
        }
        __syncthreads();
#pragma unroll
        for (int i = 0; i < 4; ++i) {
            int flat = i * 256 + tid;
            int row = flat >> 3;
            int c8 = (flat & 7) * 8;
            *(uint4*)(As + row * LDK + c8) = ra[i];
            *(uint4*)(Bs + row * LDK + c8) = rb[i];
        }
        __syncthreads();
#pragma unroll
        for (int ks = 0; ks < 2; ++ks) {
            bf16x8 af[4], bfr[4];
#pragma unroll
            for (int f = 0; f < 4; ++f) {
                af[f]  = *(const bf16x8*)(As + (wm * 64 + f * 16 + (l & 15)) * LDK + ks * 32 + (l >> 4) * 8);
                bfr[f] = *(const bf16x8*)(Bs + (wn * 64 + f * 16 + (l & 15)) * LDK + ks * 32 + (l >> 4) * 8);
            }
#pragma unroll
            for (int fm = 0; fm < 4; ++fm)
#pragma unroll
                for (int fn = 0; fn < 4; ++fn)
                    acc[fm][fn] = __builtin_amdgcn_mfma_f32_16x16x32_bf16(
                        af[fm], bfr[fn], acc[fm][fn], 0, 0, 0);
        }
    }

    const int cl = l & 15;
    const int q4 = (l >> 4) * 4;
    float b2v[4];
#pragma unroll
    for (int fn = 0; fn < 4; ++fn) b2v[fn] = b2[n0 + wn * 64 + fn * 16 + cl];
#pragma unroll
    for (int fm = 0; fm < 4; ++fm) {
#pragma unroll
        for (int r = 0; r < 4; ++r) {
            int rg = m0 + wm * 64 + fm * 16 + q4 + r; // A-row = t*B + b
            int t = rg >> 5, b = rg & 31;
            float* orow = out + (size_t)(b * T_ + t) * V_ + n0 + wn * 64 + cl;
#pragma unroll
            for (int fn = 0; fn < 4; ++fn)
                orow[fn * 16] = acc[fm][fn][r] + b2v[fn];
        }
    }
}

// ---------------------------------------------------------------------------
extern "C" void kernel_launch(void* const* d_in, const int* in_sizes, int n_in,
                              void* d_out, int out_size, void* d_ws, size_t ws_size,
                              hipStream_t stream) {
    const int* x      = (const int*)d_in[0];
    const float* init = (const float*)d_in[1];
    const float* emb  = (const float*)d_in[2];
    const float* H    = (const float*)d_in[3];
    const float* I    = (const float*)d_in[4];
    const float* b1   = (const float*)d_in[5];
    const float* U    = (const float*)d_in[6];
    const float* b2   = (const float*)d_in[7];
    float* out = (float*)d_out;

    // workspace layout:
    //   [0,8MB)     C      f32  [T*B][512]
    //   [8,12MB)    hsb    bf16 [T*B][512]
    //   [12,~45MB)  Ut     bf16 [32000][512]
    //   [46MB,..)   Hpp    u32x4 [32][1024] packed per-thread order (512 KB)
    char* ws = (char*)d_ws;
    float* C            = (float*)ws;
    unsigned short* hsb = (unsigned short*)(ws + ((size_t)8 << 20));
    unsigned short* Ut  = (unsigned short*)(ws + ((size_t)12 << 20));
    u32x4* Hpp          = (u32x4*)(ws + ((size_t)46 << 20));
    float* lastState = out + (size_t)B_ * T_ * V_;

    k_embed_proj<<<256, 512, 0, stream>>>(x, emb, I, b1, C);
    k_hpack<<<128, 256, 0, stream>>>(H, Hpp);
    k_transpose<<<dim3(500, 8), 256, 0, stream>>>(U, Ut);
    k_recur<<<B_, 1024, 0, stream>>>(C, Hpp, init, hsb, lastState);
    k_gemm<<<dim3(250, 32), 256, 0, stream>>>(hsb, Ut, b2, out);
}

// Round 9
// 1931.362 us; speedup vs baseline: 1.3170x; 1.1996x over previous
//
#include <hip/hip_runtime.h>
#include <hip/hip_bf16.h>
#include <stdint.h>

#define B_ 32
#define T_ 128
#define V_ 32000
#define E_ 256
#define HID_ 512

typedef float f32x4 __attribute__((ext_vector_type(4)));
typedef unsigned int u32x4 __attribute__((ext_vector_type(4)));
typedef __bf16 bf16x8 __attribute__((ext_vector_type(8)));

// RNE float -> bf16 bits
static __device__ __forceinline__ unsigned short f2bf(float f) {
    unsigned int u = __float_as_uint(f);
    unsigned int r = (u + 0x7fffu + ((u >> 16) & 1u)) >> 16;
    return (unsigned short)r;
}

// global -> LDS 16B async (wave-uniform base + lane*16 dest)
#define GL16(gp, lp)                                                      \
    __builtin_amdgcn_global_load_lds(                                     \
        (const __attribute__((address_space(1))) unsigned int*)(gp),      \
        (__attribute__((address_space(3))) unsigned int*)(lp), 16, 0, 0)

// ---------------------------------------------------------------------------
// K1: C[(t*B+b), :] = emb[x[b,t]] @ I + b1   (all f32)  (unchanged)
// ---------------------------------------------------------------------------
__global__ __launch_bounds__(512) void k_embed_proj(
    const int* __restrict__ x, const float* __restrict__ emb,
    const float* __restrict__ I, const float* __restrict__ b1,
    float* __restrict__ C) {
    __shared__ float e[16][E_];
    const int tid = threadIdx.x;
    const int row0 = blockIdx.x * 16;

#pragma unroll
    for (int p = 0; p < 2; ++p) {
        int flat = p * 2048 + tid * 4;
        int i = flat >> 8;
        int c = flat & 255;
        int r = row0 + i;           // global row = t*B + b
        int t = r >> 5, b = r & 31;
        int xi = x[b * T_ + t];
        *(f32x4*)&e[i][c] = *(const f32x4*)(emb + (size_t)xi * E_ + c);
    }
    __syncthreads();

    float acc[16];
#pragma unroll
    for (int i = 0; i < 16; ++i) acc[i] = 0.f;
    const int j = tid;

    for (int k4 = 0; k4 < E_ / 4; ++k4) {
        float Iv[4];
#pragma unroll
        for (int q = 0; q < 4; ++q) Iv[q] = I[(size_t)(k4 * 4 + q) * HID_ + j];
#pragma unroll
        for (int i = 0; i < 16; ++i) {
            f32x4 ev = *(const f32x4*)&e[i][k4 * 4];
            acc[i] += ev[0] * Iv[0];
            acc[i] += ev[1] * Iv[1];
            acc[i] += ev[2] * Iv[2];
            acc[i] += ev[3] * Iv[3];
        }
    }
    float bv = b1[j];
#pragma unroll
    for (int i = 0; i < 16; ++i)
        C[(size_t)(row0 + i) * HID_ + j] = acc[i] + bv;
}

// ---------------------------------------------------------------------------
// K2a: pack H (f32 [512][512]) -> Hq (u32x4 [64][512]) in k_recur's exact
// consumption order. idx = c*512 + tid; tid = (kg=tid>>6, cg=tid&63);
// pi = (c<16) ? c>>1 : 8 + ((c-16)>>1);  half = c&1;
// rows r0 = kg*64 + 2*pi (+1);  cols = cg*8 + half*4 + q.
// c<16 -> LDS-resident region, c>=16 -> streamed region.
// ---------------------------------------------------------------------------
__global__ __launch_bounds__(256) void k_hpack(const float* __restrict__ H,
                                               u32x4* __restrict__ Hq) {
    int idx = blockIdx.x * 256 + threadIdx.x;   // 0..32767
    int c = idx >> 9;
    int tid = idx & 511;
    int kg = tid >> 6, cg = tid & 63;
    int pi = (c < 16) ? (c >> 1) : (8 + ((c - 16) >> 1));
    int half = c & 1;
    int r0 = kg * 64 + 2 * pi;
    int col = cg * 8 + half * 4;
    f32x4 lo = *(const f32x4*)(H + (size_t)r0 * HID_ + col);
    f32x4 hi = *(const f32x4*)(H + (size_t)(r0 + 1) * HID_ + col);
    u32x4 o;
#pragma unroll
    for (int q = 0; q < 4; ++q)
        o[q] = (unsigned)f2bf(lo[q]) | ((unsigned)f2bf(hi[q]) << 16);
    Hq[idx] = o;
}

// ---------------------------------------------------------------------------
// K2b: transpose + convert U (f32 [512][32000]) -> Ut (bf16 [32000][512])
// ---------------------------------------------------------------------------
__global__ __launch_bounds__(256) void k_transpose(const float* __restrict__ U,
                                                   unsigned short* __restrict__ Ut) {
    __shared__ float tile[64][65];
    const int tid = threadIdx.x;
    const int n0 = blockIdx.x * 64;
    const int k0 = blockIdx.y * 64;
    const int c = tid & 63;
    const int r = tid >> 6;
#pragma unroll
    for (int it = 0; it < 16; ++it) {
        int kk = it * 4 + r;
        tile[kk][c] = U[(size_t)(k0 + kk) * V_ + n0 + c];
    }
    __syncthreads();
#pragma unroll
    for (int it = 0; it < 16; ++it) {
        int nn = it * 4 + r;
        Ut[(size_t)(n0 + nn) * HID_ + k0 + c] = f2bf(tile[c][nn]);
    }
}

// ---------------------------------------------------------------------------
// K3: recurrence, R0 skeleton + hybrid residency. 32 WGs x 512 threads.
// thread (kg=tid>>6, cg=tid&63): cols cg*8..+7, k-rows kg*64..+63 (32 pairs).
// Pairs 0..7 (16 rows) LDS-resident (HLv, 128 KB, loaded once).
// Pairs 8..31 (48 rows, 384 KB/CU/step) streamed from L2 as 6 ping-pong
// chunks of 8 coalesced u32x4 bursts, interleaved with MAC.
// f32 h, bf16 H unpack, f32 accumulate — math identical to R0.
// ---------------------------------------------------------------------------
static __device__ __forceinline__ void mac4(float* acc, u32x4 u,
                                            float hlo, float hhi, int base) {
#pragma unroll
    for (int q = 0; q < 4; ++q) {
        acc[base + q] += __uint_as_float(u[q] << 16) * hlo;
        acc[base + q] += __uint_as_float(u[q] & 0xffff0000u) * hhi;
    }
}

__global__ __launch_bounds__(512) void k_recur(
    const float* __restrict__ C, const u32x4* __restrict__ Hq,
    const float* __restrict__ init, unsigned short* __restrict__ hsb,
    float* __restrict__ lastState) {
    __shared__ u32x4 HLv[16][512];     // 128 KB: pairs 0..7 per kg-slice
    __shared__ float hbuf[2][HID_];    // 4 KB
    __shared__ float ps[8][HID_];      // 16 KB
    const int tid = threadIdx.x;
    const int b = blockIdx.x;
    const int kg = tid >> 6;           // == wave id
    const int cg = tid & 63;
    const int hb = kg * 64;

    // prologue: resident part of H -> LDS (once)
#pragma unroll
    for (int c = 0; c < 16; ++c)
        HLv[c][tid] = Hq[(size_t)c * 512 + tid];
    hbuf[0][tid] = init[b * HID_ + tid];
    __syncthreads();

    const u32x4* Hs = Hq + 16 * 512;   // streamed region base

    for (int t = 0; t < T_; ++t) {
        const int cur = t & 1;
        const float* hc = hbuf[cur];
        float cv = C[((size_t)t * B_ + b) * HID_ + tid];  // issue early
        float acc[8] = {0.f, 0.f, 0.f, 0.f, 0.f, 0.f, 0.f, 0.f};

        u32x4 sa[8], sb[8];
        // issue chunk 0 burst
#pragma unroll
        for (int u = 0; u < 8; ++u) sa[u] = Hs[(size_t)u * 512 + tid];

        // resident MAC (pairs 0..7) — covers chunk-0 latency
#pragma unroll
        for (int c = 0; c < 16; ++c) {
            u32x4 hv = HLv[c][tid];
            mac4(acc, hv, hc[hb + 2 * (c >> 1)], hc[hb + 2 * (c >> 1) + 1],
                 (c & 1) * 4);
        }

        // streamed chunks 0..5, ping-pong sa/sb (static indexing)
#pragma unroll
        for (int ch = 0; ch < 6; ch += 2) {
#pragma unroll
            for (int u = 0; u < 8; ++u)
                sb[u] = Hs[(size_t)((ch + 1) * 8 + u) * 512 + tid];
#pragma unroll
            for (int u = 0; u < 8; ++u) {
                const int pc = ch * 8 + u;
                mac4(acc, sa[u], hc[hb + 16 + 2 * (pc >> 1)],
                     hc[hb + 17 + 2 * (pc >> 1)], (pc & 1) * 4);
            }
            if (ch + 2 < 6) {
#pragma unroll
                for (int u = 0; u < 8; ++u)
                    sa[u] = Hs[(size_t)((ch + 2) * 8 + u) * 512 + tid];
            }
#pragma unroll
            for (int u = 0; u < 8; ++u) {
                const int pc = (ch + 1) * 8 + u;
                mac4(acc, sb[u], hc[hb + 16 + 2 * (pc >> 1)],
                     hc[hb + 17 + 2 * (pc >> 1)], (pc & 1) * 4);
            }
        }

        *(f32x4*)&ps[kg][cg * 8]     = *(f32x4*)&acc[0];
        *(f32x4*)&ps[kg][cg * 8 + 4] = *(f32x4*)&acc[4];
        __syncthreads();                 // ps visible; h reads done

        float v = cv;
#pragma unroll
        for (int g = 0; g < 8; ++g) v += ps[g][tid];
        v = fmaxf(v, 0.f);
        hbuf[cur ^ 1][tid] = v;
        hsb[((size_t)t * B_ + b) * HID_ + tid] = f2bf(v);
        __syncthreads();                 // h[nxt] visible
    }
    lastState[b * HID_ + tid] = hbuf[0][tid];   // T even -> final h in buf 0
}

// ---------------------------------------------------------------------------
// K4: logits = hs[4096x512](bf16) @ Ut^T (bf16 [N][K]) + b2.
// m97-style: global_load_lds 16B staging into LINEAR [128][64] LDS tiles,
// 128x128 tile, BK=64, 4 waves (2x2), 16x16x32 MFMA, single-buffered.
// grid (32 m-tiles, 250 n-tiles): consecutive blocks share the Ut n-panel.
// ---------------------------------------------------------------------------
__global__ __launch_bounds__(256) void k_gemm(
    const unsigned short* __restrict__ A, const unsigned short* __restrict__ Bt,
    const float* __restrict__ b2, float* __restrict__ out) {
    __shared__ unsigned short As[128 * 64];   // 16 KB, linear
    __shared__ unsigned short Bs[128 * 64];   // 16 KB, linear
    const int tid = threadIdx.x;
    const int l = tid & 63;
    const int w = tid >> 6;
    const int wm = w >> 1, wn = w & 1;
    const int m0 = blockIdx.x * 128;
    const int n0 = blockIdx.y * 128;

    const int srow = tid >> 3;          // staging row 0..31
    const int sc8 = (tid & 7) * 8;      // staging col (bf16 elems)

    f32x4 acc[4][4] = {};

    for (int kt = 0; kt < 8; ++kt) {
        const int kk = kt * 64;
        __syncthreads();   // previous tile's LDS reads complete
#pragma unroll
        for (int i = 0; i < 4; ++i) {
            GL16(A  + (size_t)(m0 + i * 32 + srow) * HID_ + kk + sc8,
                 (char*)As + i * 4096 + tid * 16);
            GL16(Bt + (size_t)(n0 + i * 32 + srow) * HID_ + kk + sc8,
                 (char*)Bs + i * 4096 + tid * 16);
        }
        __syncthreads();   // staged (vmcnt drained by barrier)

#pragma unroll
        for (int ks = 0; ks < 2; ++ks) {
            bf16x8 af[4], bfr[4];
#pragma unroll
            for (int f = 0; f < 4; ++f) {
                af[f]  = *(const bf16x8*)(As + (wm * 64 + f * 16 + (l & 15)) * 64 + ks * 32 + (l >> 4) * 8);
                bfr[f] = *(const bf16x8*)(Bs + (wn * 64 + f * 16 + (l & 15)) * 64 + ks * 32 + (l >> 4) * 8);
            }
#pragma unroll
            for (int fm = 0; fm < 4; ++fm)
#pragma unroll
                for (int fn = 0; fn < 4; ++fn)
                    acc[fm][fn] = __builtin_amdgcn_mfma_f32_16x16x32_bf16(
                        af[fm], bfr[fn], acc[fm][fn], 0, 0, 0);
        }
    }

    // epilogue: D col = lane&15, row = (lane>>4)*4 + reg
    const int cl = l & 15;
    const int q4 = (l >> 4) * 4;
    float b2v[4];
#pragma unroll
    for (int fn = 0; fn < 4; ++fn) b2v[fn] = b2[n0 + wn * 64 + fn * 16 + cl];
#pragma unroll
    for (int fm = 0; fm < 4; ++fm) {
#pragma unroll
        for (int r = 0; r < 4; ++r) {
            int rg = m0 + wm * 64 + fm * 16 + q4 + r; // A-row = t*B + b
            int t = rg >> 5, b = rg & 31;
            float* orow = out + (size_t)(b * T_ + t) * V_ + n0 + wn * 64 + cl;
#pragma unroll
            for (int fn = 0; fn < 4; ++fn)
                orow[fn * 16] = acc[fm][fn][r] + b2v[fn];
        }
    }
}

// ---------------------------------------------------------------------------
extern "C" void kernel_launch(void* const* d_in, const int* in_sizes, int n_in,
                              void* d_out, int out_size, void* d_ws, size_t ws_size,
                              hipStream_t stream) {
    const int* x      = (const int*)d_in[0];
    const float* init = (const float*)d_in[1];
    const float* emb  = (const float*)d_in[2];
    const float* H    = (const float*)d_in[3];
    const float* I    = (const float*)d_in[4];
    const float* b1   = (const float*)d_in[5];
    const float* U    = (const float*)d_in[6];
    const float* b2   = (const float*)d_in[7];
    float* out = (float*)d_out;

    // workspace layout:
    //   [0,8MB)     C      f32   [T*B][512]
    //   [8,12MB)    hsb    bf16  [T*B][512]
    //   [12,~45MB)  Ut     bf16  [32000][512]
    //   [46MB,..)   Hq     u32x4 [64][512] packed consumption order (512 KB)
    char* ws = (char*)d_ws;
    float* C            = (float*)ws;
    unsigned short* hsb = (unsigned short*)(ws + ((size_t)8 << 20));
    unsigned short* Ut  = (unsigned short*)(ws + ((size_t)12 << 20));
    u32x4* Hq           = (u32x4*)(ws + ((size_t)46 << 20));
    float* lastState = out + (size_t)B_ * T_ * V_;

    k_embed_proj<<<256, 512, 0, stream>>>(x, emb, I, b1, C);
    k_hpack<<<128, 256, 0, stream>>>(H, Hq);
    k_transpose<<<dim3(500, 8), 256, 0, stream>>>(U, Ut);
    k_recur<<<B_, 512, 0, stream>>>(C, Hq, init, hsb, lastState);
    k_gemm<<<dim3(32, 250), 256, 0, stream>>>(hsb, Ut, b2, out);
}